// Round 1
// baseline (78.137 us; speedup 1.0000x reference)
//
#include <hip/hip_runtime.h>

#define BATCH 4096
#define FEAT 512
#define NUM_CLASSES 10000
#define NBLK 256
#define NTHR 1024
#define ROWS_PER_BLK (BATCH / NBLK)   // 16 waves/block, 1 row per wave

// Fused center-loss: per-wave row distance -> per-block partial -> last-block
// deterministic reduce. ws layout: ws[0] = completion counter (uint, memset to
// 0 by kernel_launch), ws[64 + b] = partial of block b (atomicExch'd, so no
// init needed; 256B offset keeps it off the counter's cacheline).
__global__ __launch_bounds__(NTHR) void center_loss_fused(
    const float* __restrict__ x,
    const int* __restrict__ labels,
    const float* __restrict__ centers,
    float* __restrict__ ws,
    float* __restrict__ out) {
    const int wave = threadIdx.x >> 6;          // 0..15
    const int lane = threadIdx.x & 63;
    const int row  = blockIdx.x * ROWS_PER_BLK + wave;

    const int lbl = labels[row];
    const float4* __restrict__ xr = (const float4*)(x + (size_t)row * FEAT);
    const float4* __restrict__ cr = (const float4*)(centers + (size_t)lbl * FEAT);

    // 512 floats = 128 float4 = 2 float4/lane, fully coalesced per wave
    float4 a0 = xr[lane];
    float4 a1 = xr[lane + 64];
    float4 c0 = cr[lane];
    float4 c1 = cr[lane + 64];

    float d0 = a0.x - c0.x, d1 = a0.y - c0.y, d2 = a0.z - c0.z, d3 = a0.w - c0.w;
    float e0 = a1.x - c1.x, e1 = a1.y - c1.y, e2 = a1.z - c1.z, e3 = a1.w - c1.w;
    float acc = d0 * d0 + d1 * d1 + d2 * d2 + d3 * d3
              + e0 * e0 + e1 * e1 + e2 * e2 + e3 * e3;

#pragma unroll
    for (int off = 32; off > 0; off >>= 1)
        acc += __shfl_down(acc, off, 64);

    __shared__ float wsum[ROWS_PER_BLK];
    __shared__ int amLast;
    if (lane == 0)
        wsum[wave] = fminf(fmaxf(acc, 1e-12f), 1e12f);   // per-row clip (faithful)
    __syncthreads();

    if (threadIdx.x == 0) {
        float p = 0.0f;
#pragma unroll
        for (int i = 0; i < ROWS_PER_BLK; ++i) p += wsum[i];
        // Device-scope atomic store of this block's partial: served at the
        // MALL, so it is cross-XCD coherent without any L2 writeback fence.
        atomicExch(&ws[64 + blockIdx.x], p);
        // Order: the partial must be globally complete before we signal.
        asm volatile("s_waitcnt vmcnt(0) lgkmcnt(0)" ::: "memory");
        unsigned old = atomicAdd((unsigned int*)ws, 1u);
        amLast = (old == (unsigned)(NBLK - 1));
    }
    __syncthreads();

    // Last block to finish reduces the 256 partials in a FIXED order
    // (deterministic result, independent of block completion order).
    if (amLast && wave == 0) {
        // atomic-add-zero = coherent read through the MALL
        float t = atomicAdd(&ws[64 + lane],        0.0f)
                + atomicAdd(&ws[64 + 64 + lane],   0.0f)
                + atomicAdd(&ws[64 + 128 + lane],  0.0f)
                + atomicAdd(&ws[64 + 192 + lane],  0.0f);
#pragma unroll
        for (int off = 32; off > 0; off >>= 1)
            t += __shfl_down(t, off, 64);
        if (lane == 0)
            out[0] = t * (1.0f / (float)BATCH)
                   + (float)((double)(NUM_CLASSES - 1) * 1e-12);
    }
}

extern "C" void kernel_launch(void* const* d_in, const int* in_sizes, int n_in,
                              void* d_out, int out_size, void* d_ws, size_t ws_size,
                              hipStream_t stream) {
    const float* x       = (const float*)d_in[0];
    const int*   labels  = (const int*)d_in[1];
    const float* centers = (const float*)d_in[2];

    // Zero only the 4-byte completion counter (capturable memset node).
    hipMemsetAsync(d_ws, 0, 4, stream);
    center_loss_fused<<<NBLK, NTHR, 0, stream>>>(x, labels, centers,
                                                 (float*)d_ws, (float*)d_out);
}

// Round 3
// 75.145 us; speedup vs baseline: 1.0398x; 1.0398x over previous
//
#include <hip/hip_runtime.h>

#define BATCH 4096
#define FEAT 512
#define NUM_CLASSES 10000

// Native clang vector type — __builtin_nontemporal_load requires a vector of
// scalars, not HIP's HIP_vector_type struct.
typedef float floatx4 __attribute__((ext_vector_type(4)));

// Stage 1: one wave (64 lanes) per batch row -> squared distance to its center.
// Writes per-row partial to ws[row]. No atomics.
// x is streamed non-temporally (zero reuse) so the 8 MB stream doesn't evict
// gathered center rows (~1.2x reuse) from the per-XCD L2s.
__global__ __launch_bounds__(256) void center_loss_dist(
    const float* __restrict__ x,
    const int* __restrict__ labels,
    const float* __restrict__ centers,
    float* __restrict__ ws) {
    const int wave = threadIdx.x >> 6;          // 0..3
    const int lane = threadIdx.x & 63;
    const int row  = blockIdx.x * 4 + wave;

    const int lbl = labels[row];
    const floatx4* __restrict__ xr = (const floatx4*)(x + (size_t)row * FEAT);
    const floatx4* __restrict__ cr = (const floatx4*)(centers + (size_t)lbl * FEAT);

    // 512 floats = 128 float4 = 2 float4/lane
    floatx4 a0 = __builtin_nontemporal_load(&xr[lane]);
    floatx4 a1 = __builtin_nontemporal_load(&xr[lane + 64]);
    floatx4 c0 = cr[lane];
    floatx4 c1 = cr[lane + 64];

    floatx4 d = a0 - c0;
    floatx4 e = a1 - c1;
    float acc = d.x * d.x + d.y * d.y + d.z * d.z + d.w * d.w
              + e.x * e.x + e.y * e.y + e.z * e.z + e.w * e.w;

#pragma unroll
    for (int off = 32; off > 0; off >>= 1)
        acc += __shfl_down(acc, off, 64);

    if (lane == 0) __builtin_nontemporal_store(acc, &ws[row]);
}

// Stage 2: single block reduces the 4096 partials (clip each, sum, scale)
// and adds the exact clip-floor background term (B*C - B)*1e-12 / B.
__global__ __launch_bounds__(1024) void center_loss_reduce(
    const float* __restrict__ ws,
    float* __restrict__ out) {
    const int tid = threadIdx.x;
    const floatx4 v = ((const floatx4*)ws)[tid];   // 1024 threads * 4 = 4096

    float s = fminf(fmaxf(v.x, 1e-12f), 1e12f)
            + fminf(fmaxf(v.y, 1e-12f), 1e12f)
            + fminf(fmaxf(v.z, 1e-12f), 1e12f)
            + fminf(fmaxf(v.w, 1e-12f), 1e12f);

#pragma unroll
    for (int off = 32; off > 0; off >>= 1)
        s += __shfl_down(s, off, 64);

    __shared__ float warp_sums[16];
    const int wave = tid >> 6;
    const int lane = tid & 63;
    if (lane == 0) warp_sums[wave] = s;
    __syncthreads();

    if (wave == 0) {
        float t = (lane < 16) ? warp_sums[lane] : 0.0f;
#pragma unroll
        for (int off = 8; off > 0; off >>= 1)
            t += __shfl_down(t, off, 64);
        if (lane == 0) {
            out[0] = t * (1.0f / (float)BATCH)
                   + (float)((double)(NUM_CLASSES - 1) * 1e-12);
        }
    }
}

extern "C" void kernel_launch(void* const* d_in, const int* in_sizes, int n_in,
                              void* d_out, int out_size, void* d_ws, size_t ws_size,
                              hipStream_t stream) {
    const float* x       = (const float*)d_in[0];
    const int*   labels  = (const int*)d_in[1];
    const float* centers = (const float*)d_in[2];
    float* out = (float*)d_out;
    float* ws  = (float*)d_ws;

    center_loss_dist<<<BATCH / 4, 256, 0, stream>>>(x, labels, centers, ws);
    center_loss_reduce<<<1, 1024, 0, stream>>>(ws, out);
}

// Round 4
// 74.562 us; speedup vs baseline: 1.0479x; 1.0078x over previous
//
#include <hip/hip_runtime.h>

#define BATCH 4096
#define FEAT 512
#define NUM_CLASSES 10000

// Stage 1: one wave (64 lanes) per batch row -> squared distance to its center.
// Writes per-row partial to ws[row]. No atomics.
// NOTE: nontemporal variants of the x-loads / ws-store were tried (R3) and
// were neutral-to-negative (nt ws-store forces stage-2's read to miss L2).
__global__ __launch_bounds__(256) void center_loss_dist(
    const float* __restrict__ x,
    const int* __restrict__ labels,
    const float* __restrict__ centers,
    float* __restrict__ ws) {
    const int wave = threadIdx.x >> 6;          // 0..3
    const int lane = threadIdx.x & 63;
    const int row  = blockIdx.x * 4 + wave;

    const int lbl = labels[row];
    const float4* __restrict__ xr = (const float4*)(x + (size_t)row * FEAT);
    const float4* __restrict__ cr = (const float4*)(centers + (size_t)lbl * FEAT);

    // 512 floats = 128 float4 = 2 float4/lane
    float4 a0 = xr[lane];
    float4 a1 = xr[lane + 64];
    float4 c0 = cr[lane];
    float4 c1 = cr[lane + 64];

    float d0 = a0.x - c0.x, d1 = a0.y - c0.y, d2 = a0.z - c0.z, d3 = a0.w - c0.w;
    float e0 = a1.x - c1.x, e1 = a1.y - c1.y, e2 = a1.z - c1.z, e3 = a1.w - c1.w;
    float acc = d0 * d0 + d1 * d1 + d2 * d2 + d3 * d3
              + e0 * e0 + e1 * e1 + e2 * e2 + e3 * e3;

#pragma unroll
    for (int off = 32; off > 0; off >>= 1)
        acc += __shfl_down(acc, off, 64);

    if (lane == 0) ws[row] = acc;
}

// Stage 2: single block reduces the 4096 partials (clip each, sum, scale)
// and adds the exact clip-floor background term (B*C - B)*1e-12 / B.
__global__ __launch_bounds__(1024) void center_loss_reduce(
    const float* __restrict__ ws,
    float* __restrict__ out) {
    const int tid = threadIdx.x;
    const float4 v = ((const float4*)ws)[tid];   // 1024 threads * 4 = 4096

    float s = fminf(fmaxf(v.x, 1e-12f), 1e12f)
            + fminf(fmaxf(v.y, 1e-12f), 1e12f)
            + fminf(fmaxf(v.z, 1e-12f), 1e12f)
            + fminf(fmaxf(v.w, 1e-12f), 1e12f);

#pragma unroll
    for (int off = 32; off > 0; off >>= 1)
        s += __shfl_down(s, off, 64);

    __shared__ float warp_sums[16];
    const int wave = tid >> 6;
    const int lane = tid & 63;
    if (lane == 0) warp_sums[wave] = s;
    __syncthreads();

    if (wave == 0) {
        float t = (lane < 16) ? warp_sums[lane] : 0.0f;
#pragma unroll
        for (int off = 8; off > 0; off >>= 1)
            t += __shfl_down(t, off, 64);
        if (lane == 0) {
            out[0] = t * (1.0f / (float)BATCH)
                   + (float)((double)(NUM_CLASSES - 1) * 1e-12);
        }
    }
}

extern "C" void kernel_launch(void* const* d_in, const int* in_sizes, int n_in,
                              void* d_out, int out_size, void* d_ws, size_t ws_size,
                              hipStream_t stream) {
    const float* x       = (const float*)d_in[0];
    const int*   labels  = (const int*)d_in[1];
    const float* centers = (const float*)d_in[2];
    float* out = (float*)d_out;
    float* ws  = (float*)d_ws;

    center_loss_dist<<<BATCH / 4, 256, 0, stream>>>(x, labels, centers, ws);
    center_loss_reduce<<<1, 1024, 0, stream>>>(ws, out);
}